// Round 1
// baseline (433.287 us; speedup 1.0000x reference)
//
#include <hip/hip_runtime.h>
#include <hip/hip_bf16.h>

// R0: correct fp32 baseline with the algebraic decomposition:
//   t[b,(n,r)] = sum_a V[n,r,a] * h_A[b,a]          (GEMM1: 2048x2048, K=256)
//   s = alpha[b,n] * t[b,(n,r)]  (stored bf16 in ws -> pre-validates MFMA numerics)
//   pre[b,c] = [s | h_A | alpha] @ [Uflat ; W_base^T ; bias]   (GEMM2: K=2816)
//   out = LN(h_A + gamma*(pre + b_base)) * ln_scale + ln_bias
// ws layout: s_bf16 8MB | Ut f32 2MB | pre f32 2MB  (12MB total)

#define B_   2048
#define N_   512
#define D_   4096
#define DA_  256
#define DB_  256
#define K1_  2048   // N*R
#define KU_  2048   // end of s segment in concatenated K
#define KW_  2304   // end of h_A/W_base segment
#define KT_  2816   // total concatenated K

// ---- P: gather Uflat[k][c] = pool[n, c*4+r], k = n*4+r (k-major, coalesced reads later)
__global__ __launch_bounds__(256) void prep_ut(const float* __restrict__ pool,
                                               float* __restrict__ Ut) {
    int idx = blockIdx.x * 256 + threadIdx.x;   // K1_*DB_ total
    int k = idx >> 8;
    int c = idx & 255;
    Ut[idx] = pool[(size_t)(k >> 2) * D_ + (c << 2) + (k & 3)];
}

// ---- K1: s[b,k] = alpha[b, k>>2] * sum_a h_A[b,a] * pool[k>>2, 1024 + (k&3)*256 + a]
// tile 64(b) x 64(k), K=256 in 4 chunks of 64; 4x4 register blocking per thread
__global__ __launch_bounds__(256) void k1_s(const float* __restrict__ hA,
                                            const float* __restrict__ pool,
                                            const float* __restrict__ alpha,
                                            __hip_bfloat16* __restrict__ s) {
    __shared__ float Ah[64][65];   // +1 pad: bank-conflict-free row reads
    __shared__ float Vv[64][65];
    const int b0 = blockIdx.y * 64;
    const int k0 = blockIdx.x * 64;
    const int t  = threadIdx.x;
    const int r0 = (t >> 4) * 4;   // 0..60
    const int c0 = (t & 15) * 4;   // 0..60
    float acc[4][4] = {};

    for (int ka = 0; ka < DA_; ka += 64) {
        for (int x = t; x < 64 * 64; x += 256) {
            int rr = x >> 6, cc = x & 63;
            Ah[rr][cc] = hA[(size_t)(b0 + rr) * DA_ + ka + cc];
            int kk = k0 + rr;
            Vv[rr][cc] = pool[(size_t)(kk >> 2) * D_ + 1024 + (kk & 3) * 256 + ka + cc];
        }
        __syncthreads();
        #pragma unroll 8
        for (int aa = 0; aa < 64; ++aa) {
            float ar[4], vr[4];
            #pragma unroll
            for (int ii = 0; ii < 4; ++ii) ar[ii] = Ah[r0 + ii][aa];
            #pragma unroll
            for (int jj = 0; jj < 4; ++jj) vr[jj] = Vv[c0 + jj][aa];
            #pragma unroll
            for (int ii = 0; ii < 4; ++ii)
                #pragma unroll
                for (int jj = 0; jj < 4; ++jj)
                    acc[ii][jj] += ar[ii] * vr[jj];
        }
        __syncthreads();
    }
    #pragma unroll
    for (int ii = 0; ii < 4; ++ii)
        #pragma unroll
        for (int jj = 0; jj < 4; ++jj) {
            int b = b0 + r0 + ii, k = k0 + c0 + jj;
            float v = acc[ii][jj] * alpha[(size_t)b * N_ + (k >> 2)];
            s[(size_t)b * K1_ + k] = __float2bfloat16(v);
        }
}

// ---- K2: pre[b,c] over concatenated K=2816; tile 32(b) x 128(c), chunks of 64
__global__ __launch_bounds__(256) void k2_pre(const __hip_bfloat16* __restrict__ s,
                                              const float* __restrict__ Ut,
                                              const float* __restrict__ hA,
                                              const float* __restrict__ alpha,
                                              const float* __restrict__ Wb,
                                              const float* __restrict__ pool,
                                              float* __restrict__ pre) {
    __shared__ float Xl[32][65];
    __shared__ float Ml[64][129];
    const int b0  = blockIdx.y * 32;
    const int cb0 = blockIdx.x * 128;
    const int t   = threadIdx.x;
    const int r0  = (t >> 5) * 4;    // 0..28
    const int c0  = (t & 31) * 4;    // 0..124
    float acc[4][4] = {};

    for (int kc = 0; kc < KT_; kc += 64) {
        // X chunk: 32 rows x 64 k  (segment boundaries 2048/2304 are multiples of 64)
        for (int x = t; x < 32 * 64; x += 256) {
            int rr = x >> 6, cc = x & 63;
            int kk = kc + cc, b = b0 + rr;
            float v;
            if (kk < KU_)      v = __bfloat162float(s[(size_t)b * K1_ + kk]);
            else if (kk < KW_) v = hA[(size_t)b * DA_ + (kk - KU_)];
            else               v = alpha[(size_t)b * N_ + (kk - KW_)];
            Xl[rr][cc] = v;
        }
        // M chunk: 64 k x 128 c
        for (int x = t; x < 64 * 128; x += 256) {
            int rr = x >> 7, cc = x & 127;
            int kk = kc + rr, c = cb0 + cc;
            float v;
            if (kk < KU_)      v = Ut[(size_t)kk * DB_ + c];
            else if (kk < KW_) v = Wb[(size_t)c * DA_ + (kk - KU_)];
            else               v = pool[(size_t)(kk - KW_) * D_ + 2048 + c];
            Ml[rr][cc] = v;
        }
        __syncthreads();
        #pragma unroll 8
        for (int cc = 0; cc < 64; ++cc) {
            float xr[4], mr[4];
            #pragma unroll
            for (int ii = 0; ii < 4; ++ii) xr[ii] = Xl[r0 + ii][cc];
            #pragma unroll
            for (int jj = 0; jj < 4; ++jj) mr[jj] = Ml[cc][c0 + jj];
            #pragma unroll
            for (int ii = 0; ii < 4; ++ii)
                #pragma unroll
                for (int jj = 0; jj < 4; ++jj)
                    acc[ii][jj] += xr[ii] * mr[jj];
        }
        __syncthreads();
    }
    #pragma unroll
    for (int ii = 0; ii < 4; ++ii)
        #pragma unroll
        for (int jj = 0; jj < 4; ++jj)
            pre[(size_t)(b0 + r0 + ii) * DB_ + cb0 + c0 + jj] = acc[ii][jj];
}

// ---- K3: y = hA + gamma*(pre + b_base); LayerNorm over 256; one wave per row
__global__ __launch_bounds__(256) void k3_ln(const float* __restrict__ pre,
                                             const float* __restrict__ hA,
                                             const float* __restrict__ bb,
                                             const float* __restrict__ gamma_p,
                                             const float* __restrict__ lns,
                                             const float* __restrict__ lnb,
                                             float* __restrict__ out) {
    const int wave = threadIdx.x >> 6;
    const int lane = threadIdx.x & 63;
    const int b = blockIdx.x * 4 + wave;
    const float g = gamma_p[0];
    const size_t base = (size_t)b * DB_ + lane * 4;

    float4 p  = *(const float4*)&pre[base];
    float4 h  = *(const float4*)&hA[base];
    float4 b4 = *(const float4*)&bb[lane * 4];
    float y0 = h.x + g * (p.x + b4.x);
    float y1 = h.y + g * (p.y + b4.y);
    float y2 = h.z + g * (p.z + b4.z);
    float y3 = h.w + g * (p.w + b4.w);

    float sum = y0 + y1 + y2 + y3;
    float ss  = y0*y0 + y1*y1 + y2*y2 + y3*y3;
    #pragma unroll
    for (int off = 1; off < 64; off <<= 1) {
        sum += __shfl_xor(sum, off);
        ss  += __shfl_xor(ss, off);
    }
    float mu  = sum * (1.0f / 256.0f);
    float var = ss * (1.0f / 256.0f) - mu * mu;
    float inv = rsqrtf(var + 1e-5f);

    float4 sc = *(const float4*)&lns[lane * 4];
    float4 bi = *(const float4*)&lnb[lane * 4];
    float4 o;
    o.x = (y0 - mu) * inv * sc.x + bi.x;
    o.y = (y1 - mu) * inv * sc.y + bi.y;
    o.z = (y2 - mu) * inv * sc.z + bi.z;
    o.w = (y3 - mu) * inv * sc.w + bi.w;
    *(float4*)&out[base] = o;
}

extern "C" void kernel_launch(void* const* d_in, const int* in_sizes, int n_in,
                              void* d_out, int out_size, void* d_ws, size_t ws_size,
                              hipStream_t stream) {
    const float* hA    = (const float*)d_in[0];
    const float* pool  = (const float*)d_in[1];
    const float* alpha = (const float*)d_in[2];
    const float* Wb    = (const float*)d_in[3];
    const float* bb    = (const float*)d_in[4];
    const float* gamma = (const float*)d_in[5];
    const float* lns   = (const float*)d_in[6];
    const float* lnb   = (const float*)d_in[7];
    float* out = (float*)d_out;

    char* ws = (char*)d_ws;
    __hip_bfloat16* s = (__hip_bfloat16*)ws;                                   // 8 MB
    float* Ut  = (float*)(ws + (size_t)B_ * K1_ * 2);                          // 2 MB
    float* pre = (float*)(ws + (size_t)B_ * K1_ * 2 + (size_t)K1_ * DB_ * 4);  // 2 MB

    prep_ut<<<(K1_ * DB_) / 256, 256, 0, stream>>>(pool, Ut);
    k1_s  <<<dim3(K1_ / 64, B_ / 64), 256, 0, stream>>>(hA, pool, alpha, s);
    k2_pre<<<dim3(DB_ / 128, B_ / 32), 256, 0, stream>>>(s, Ut, hA, alpha, Wb, pool, pre);
    k3_ln <<<B_ / 4, 256, 0, stream>>>(pre, hA, bb, gamma, lns, lnb, out);
}

// Round 2
// 44.329 us; speedup vs baseline: 9.7744x; 9.7744x over previous
//
#include <hip/hip_runtime.h>
#include <hip/hip_bf16.h>

// R2: full MFMA bf16 port.
//   X [2048][2816] bf16 = [ s(2048) | hA(256) | alpha(512) ]   (unified A matrix)
//   GEMM1: s[b,k] = alpha[b,k>>2] * sum_a hA[b,a]*V'[k,a]   (V'[k][a] k-major bf16)
//   GEMM2: pre[b,c] = sum_k X[b,k]*Mt[c,k],  Mt = [U ; W_base^T ; bias] [256][2816]
//          split-K x4 -> f32 partials (deterministic, no atomics)
//   LN:    out = LN(hA + gamma*(pre + b_base)) * ln_scale + ln_bias
// ws: X 11.53MB | Vb 1MB | Mt 1.44MB | part 8MB  = 21.4MB

typedef __attribute__((ext_vector_type(8))) short bf16x8;
typedef __attribute__((ext_vector_type(4))) float f32x4;
typedef unsigned short ushort_t;

#define LDA_X 2816
#define N_POOL 512
#define D_POOL 4096

__device__ __forceinline__ void gld16(const ushort_t* g, ushort_t* l) {
    __builtin_amdgcn_global_load_lds((__attribute__((address_space(1))) void*)g,
                                     (__attribute__((address_space(3))) void*)l, 16, 0, 0);
}

// ---- prep: assemble X (hA, alpha segments), Vb, Mt — all bf16
__global__ __launch_bounds__(256) void prep(const float* __restrict__ hA,
                                            const float* __restrict__ pool,
                                            const float* __restrict__ alpha,
                                            const float* __restrict__ Wb,
                                            __hip_bfloat16* __restrict__ Xb,
                                            __hip_bfloat16* __restrict__ Vb,
                                            __hip_bfloat16* __restrict__ Mtb) {
    const int t = threadIdx.x;
    const int idx = blockIdx.x * 256 + t;
    switch (blockIdx.y) {
    case 0: {  // X hA segment: [2048][256]
        if (idx < 2048 * 256) {
            int b = idx >> 8, a = idx & 255;
            Xb[(size_t)b * LDA_X + 2048 + a] = __float2bfloat16(hA[idx]);
        }
        break; }
    case 1: {  // X alpha segment: [2048][512]
        if (idx < 2048 * 512) {
            int b = idx >> 9, j = idx & 511;
            Xb[(size_t)b * LDA_X + 2304 + j] = __float2bfloat16(alpha[idx]);
        }
        break; }
    case 2: {  // Vb[k][a] = pool[k>>2, 1024 + (k&3)*256 + a]
        if (idx < 2048 * 256) {
            int k = idx >> 8, a = idx & 255;
            Vb[idx] = __float2bfloat16(pool[(size_t)(k >> 2) * D_POOL + 1024 + (k & 3) * 256 + a]);
        }
        break; }
    default: { // Mt[c][kk]: U / W_base^T / bias
        if (blockIdx.x < 256 * 11) {
            int c = blockIdx.x / 11;
            int kk = (blockIdx.x % 11) * 256 + t;
            float v;
            if (kk < 2048)       v = pool[(size_t)(kk >> 2) * D_POOL + (c << 2) + (kk & 3)];
            else if (kk < 2304)  v = Wb[(size_t)c * 256 + (kk - 2048)];
            else                 v = pool[(size_t)(kk - 2304) * D_POOL + 2048 + c];
            Mtb[(size_t)c * LDA_X + kk] = __float2bfloat16(v);
        }
        break; }
    }
}

// ---- GEMM1: 128x128 tile, 4 waves (2x2, each 64x64), BK=32, K=256
__global__ __launch_bounds__(256) void k1_gemm(ushort_t* __restrict__ Xu,
                                               const ushort_t* __restrict__ Vb,
                                               const float* __restrict__ alpha) {
    __shared__ __align__(16) ushort_t As[128 * 32];
    __shared__ __align__(16) ushort_t Bs[128 * 32];
    const int t = threadIdx.x;
    const int w = t >> 6, l = t & 63, l16 = l & 15, l4 = l >> 4;
    const int wr = w >> 1, wc = w & 1;
    const int bm0 = blockIdx.y * 128, bn0 = blockIdx.x * 128;
    const ushort_t* A = Xu + 2048;   // hA segment, lda = 2816
    const int rA = t >> 2;           // 0..63
    const int kA = (t & 3) * 8;

    f32x4 acc[4][4];
    #pragma unroll
    for (int i = 0; i < 4; ++i)
        #pragma unroll
        for (int j = 0; j < 4; ++j) acc[i][j] = (f32x4){0.f, 0.f, 0.f, 0.f};

    for (int k0 = 0; k0 < 256; k0 += 32) {
        gld16(A  + (size_t)(bm0 + rA)      * LDA_X + k0 + kA, As + (w << 9));
        gld16(A  + (size_t)(bm0 + 64 + rA) * LDA_X + k0 + kA, As + 2048 + (w << 9));
        gld16(Vb + (size_t)(bn0 + rA)      * 256   + k0 + kA, Bs + (w << 9));
        gld16(Vb + (size_t)(bn0 + 64 + rA) * 256   + k0 + kA, Bs + 2048 + (w << 9));
        __syncthreads();
        bf16x8 af[4], bfr[4];
        #pragma unroll
        for (int mi = 0; mi < 4; ++mi)
            af[mi] = *(const bf16x8*)(As + (wr * 64 + mi * 16 + l16) * 32 + l4 * 8);
        #pragma unroll
        for (int ni = 0; ni < 4; ++ni)
            bfr[ni] = *(const bf16x8*)(Bs + (wc * 64 + ni * 16 + l16) * 32 + l4 * 8);
        #pragma unroll
        for (int mi = 0; mi < 4; ++mi)
            #pragma unroll
            for (int ni = 0; ni < 4; ++ni)
                acc[mi][ni] = __builtin_amdgcn_mfma_f32_16x16x32_bf16(af[mi], bfr[ni], acc[mi][ni], 0, 0, 0);
        __syncthreads();
    }
    __hip_bfloat16* Xb = (__hip_bfloat16*)Xu;
    #pragma unroll
    for (int mi = 0; mi < 4; ++mi)
        #pragma unroll
        for (int ni = 0; ni < 4; ++ni)
            #pragma unroll
            for (int e = 0; e < 4; ++e) {
                int b = bm0 + wr * 64 + mi * 16 + l4 * 4 + e;
                int k = bn0 + wc * 64 + ni * 16 + l16;
                float v = acc[mi][ni][e] * alpha[(size_t)b * N_POOL + (k >> 2)];
                Xb[(size_t)b * LDA_X + k] = __float2bfloat16(v);
            }
}

// ---- GEMM2: 64x64 tile, 4 waves (2x2, each 32x32), BK=32, split-K x4 (704 each)
__global__ __launch_bounds__(256) void k2_gemm(const ushort_t* __restrict__ Xu,
                                               const ushort_t* __restrict__ Mt,
                                               float* __restrict__ part) {
    __shared__ __align__(16) ushort_t As[64 * 32];
    __shared__ __align__(16) ushort_t Bs[64 * 32];
    const int t = threadIdx.x;
    const int w = t >> 6, l = t & 63, l16 = l & 15, l4 = l >> 4;
    const int wr = w >> 1, wc = w & 1;
    const int bm0 = blockIdx.x * 64, bn0 = blockIdx.y * 64;
    const int kc0 = blockIdx.z * 704;
    const int rA = t >> 2, kA = (t & 3) * 8;

    f32x4 acc[2][2];
    #pragma unroll
    for (int i = 0; i < 2; ++i)
        #pragma unroll
        for (int j = 0; j < 2; ++j) acc[i][j] = (f32x4){0.f, 0.f, 0.f, 0.f};

    for (int kk = 0; kk < 704; kk += 32) {
        const int k0 = kc0 + kk;
        gld16(Xu + (size_t)(bm0 + rA) * LDA_X + k0 + kA, As + (w << 9));
        gld16(Mt + (size_t)(bn0 + rA) * LDA_X + k0 + kA, Bs + (w << 9));
        __syncthreads();
        bf16x8 af[2], bfr[2];
        #pragma unroll
        for (int mi = 0; mi < 2; ++mi)
            af[mi] = *(const bf16x8*)(As + (wr * 32 + mi * 16 + l16) * 32 + l4 * 8);
        #pragma unroll
        for (int ni = 0; ni < 2; ++ni)
            bfr[ni] = *(const bf16x8*)(Bs + (wc * 32 + ni * 16 + l16) * 32 + l4 * 8);
        #pragma unroll
        for (int mi = 0; mi < 2; ++mi)
            #pragma unroll
            for (int ni = 0; ni < 2; ++ni)
                acc[mi][ni] = __builtin_amdgcn_mfma_f32_16x16x32_bf16(af[mi], bfr[ni], acc[mi][ni], 0, 0, 0);
        __syncthreads();
    }
    float* P = part + (size_t)blockIdx.z * (2048 * 256);
    #pragma unroll
    for (int mi = 0; mi < 2; ++mi)
        #pragma unroll
        for (int ni = 0; ni < 2; ++ni)
            #pragma unroll
            for (int e = 0; e < 4; ++e) {
                int b = bm0 + wr * 32 + mi * 16 + l4 * 4 + e;
                int c = bn0 + wc * 32 + ni * 16 + l16;
                P[(size_t)b * 256 + c] = acc[mi][ni][e];
            }
}

// ---- LN: sum 4 partials + b_base; residual; LayerNorm over 256; 1 wave/row
__global__ __launch_bounds__(256) void k3_ln(const float* __restrict__ part,
                                             const float* __restrict__ hA,
                                             const float* __restrict__ bb,
                                             const float* __restrict__ gamma_p,
                                             const float* __restrict__ lns,
                                             const float* __restrict__ lnb,
                                             float* __restrict__ out) {
    const int wave = threadIdx.x >> 6;
    const int lane = threadIdx.x & 63;
    const int b = blockIdx.x * 4 + wave;
    const float g = gamma_p[0];
    const size_t base = (size_t)b * 256 + lane * 4;

    float4 p = *(const float4*)&part[base];
    #pragma unroll
    for (int z = 1; z < 4; ++z) {
        float4 q = *(const float4*)&part[(size_t)z * 2048 * 256 + base];
        p.x += q.x; p.y += q.y; p.z += q.z; p.w += q.w;
    }
    float4 h  = *(const float4*)&hA[base];
    float4 b4 = *(const float4*)&bb[lane * 4];
    float y0 = h.x + g * (p.x + b4.x);
    float y1 = h.y + g * (p.y + b4.y);
    float y2 = h.z + g * (p.z + b4.z);
    float y3 = h.w + g * (p.w + b4.w);

    float sum = y0 + y1 + y2 + y3;
    float ss  = y0*y0 + y1*y1 + y2*y2 + y3*y3;
    #pragma unroll
    for (int off = 1; off < 64; off <<= 1) {
        sum += __shfl_xor(sum, off);
        ss  += __shfl_xor(ss, off);
    }
    float mu  = sum * (1.0f / 256.0f);
    float var = ss * (1.0f / 256.0f) - mu * mu;
    float inv = rsqrtf(var + 1e-5f);

    float4 sc = *(const float4*)&lns[lane * 4];
    float4 bi = *(const float4*)&lnb[lane * 4];
    float4 o;
    o.x = (y0 - mu) * inv * sc.x + bi.x;
    o.y = (y1 - mu) * inv * sc.y + bi.y;
    o.z = (y2 - mu) * inv * sc.z + bi.z;
    o.w = (y3 - mu) * inv * sc.w + bi.w;
    *(float4*)&out[base] = o;
}

extern "C" void kernel_launch(void* const* d_in, const int* in_sizes, int n_in,
                              void* d_out, int out_size, void* d_ws, size_t ws_size,
                              hipStream_t stream) {
    const float* hA    = (const float*)d_in[0];
    const float* pool  = (const float*)d_in[1];
    const float* alpha = (const float*)d_in[2];
    const float* Wb    = (const float*)d_in[3];
    const float* bb    = (const float*)d_in[4];
    const float* gamma = (const float*)d_in[5];
    const float* lns   = (const float*)d_in[6];
    const float* lnb   = (const float*)d_in[7];
    float* out = (float*)d_out;

    ushort_t* Xu = (ushort_t*)d_ws;                  // [2048][2816] bf16
    ushort_t* Vb = Xu + (size_t)2048 * 2816;         // [2048][256]  bf16
    ushort_t* Mt = Vb + (size_t)2048 * 256;          // [256][2816]  bf16
    float*  part = (float*)(Mt + (size_t)256 * 2816); // [4][2048][256] f32

    prep<<<dim3(4096, 4), 256, 0, stream>>>(hA, pool, alpha, Wb,
                                            (__hip_bfloat16*)Xu, (__hip_bfloat16*)Vb,
                                            (__hip_bfloat16*)Mt);
    k1_gemm<<<dim3(16, 16), 256, 0, stream>>>(Xu, Vb, alpha);
    k2_gemm<<<dim3(32, 4, 4), 256, 0, stream>>>(Xu, Mt, part);
    k3_ln<<<512, 256, 0, stream>>>(part, hA, bb, gamma, lns, lnb, out);
}

// Round 3
// 34.139 us; speedup vs baseline: 12.6920x; 1.2985x over previous
//
#include <hip/hip_runtime.h>
#include <hip/hip_bf16.h>

// R3: occupancy + 2-phase pipeline + LDS swizzle.
//   X [2048][2816] bf16 = [ s(2048) | hA(256) | alpha(512) ]
//   GEMM1 (k1): s[b,k] = alpha[b,k>>2] * sum_a hA[b,a]*V'[k,a]; 64x64 tiles, grid 1024
//   GEMM2 (k2): pre[b,c] = sum_k X[b,k]*Mt[c,k]; split-K x4 -> f32 partials; grid 512
//   LN (k3):    out = LN(hA + gamma*(pre + b_base)) * ln_scale + ln_bias
// Both GEMMs: BK=64, double-buffered LDS, stage-before-compute (T3 2-phase),
// XOR-(row&7) chunk swizzle applied source-side (rule #21) + on ds_read.
// ws: X 11.53MB | Vb 1MB | Mt 1.44MB | part 8MB

typedef __attribute__((ext_vector_type(8))) short bf16x8;
typedef __attribute__((ext_vector_type(4))) float f32x4;
typedef unsigned short ushort_t;

#define LDA_X 2816
#define N_POOL 512
#define D_POOL 4096

__device__ __forceinline__ void gld16(const ushort_t* g, ushort_t* l) {
    __builtin_amdgcn_global_load_lds((__attribute__((address_space(1))) void*)g,
                                     (__attribute__((address_space(3))) void*)l, 16, 0, 0);
}

__device__ __forceinline__ void write4(ushort_t* p, float4 v) {
    union { __hip_bfloat16 h; ushort_t u; } c0, c1, c2, c3;
    c0.h = __float2bfloat16(v.x); c1.h = __float2bfloat16(v.y);
    c2.h = __float2bfloat16(v.z); c3.h = __float2bfloat16(v.w);
    ushort4 w = {c0.u, c1.u, c2.u, c3.u};
    *(ushort4*)p = w;
}

// ---- prep: assemble X(hA,alpha), Vb, Mt — float4-vectorized
__global__ __launch_bounds__(256) void prep(const float* __restrict__ hA,
                                            const float* __restrict__ pool,
                                            const float* __restrict__ alpha,
                                            const float* __restrict__ Wb,
                                            ushort_t* __restrict__ Xb,
                                            ushort_t* __restrict__ Vb,
                                            ushort_t* __restrict__ Mt) {
    const int bid = blockIdx.x, t = threadIdx.x;
    if (bid < 512) {                    // X hA segment [2048][256]
        int idx = bid * 256 + t, b = idx >> 6, a4 = (idx & 63) << 2;
        float4 v = *(const float4*)&hA[(size_t)b * 256 + a4];
        write4(Xb + (size_t)b * LDA_X + 2048 + a4, v);
    } else if (bid < 1536) {            // X alpha segment [2048][512]
        int idx = (bid - 512) * 256 + t, b = idx >> 7, j4 = (idx & 127) << 2;
        float4 v = *(const float4*)&alpha[(size_t)b * 512 + j4];
        write4(Xb + (size_t)b * LDA_X + 2304 + j4, v);
    } else if (bid < 2048) {            // Vb[k][a] = pool[k>>2, 1024+(k&3)*256+a]
        int idx = (bid - 1536) * 256 + t, k = idx >> 6, a4 = (idx & 63) << 2;
        float4 v = *(const float4*)&pool[(size_t)(k >> 2) * D_POOL + 1024 + (k & 3) * 256 + a4];
        write4(Vb + (size_t)k * 256 + a4, v);
    } else if (bid < 2560) {            // Mt U: Mt[c][4n..4n+3] = pool[n][4c..4c+3]
        int idx = (bid - 2048) * 256 + t, c = idx >> 9, n = idx & 511;
        float4 v = *(const float4*)&pool[(size_t)n * D_POOL + (c << 2)];
        write4(Mt + (size_t)c * LDA_X + (n << 2), v);
    } else if (bid < 2624) {            // Mt Wb: [c][2048+q]
        int idx = (bid - 2560) * 256 + t, c = idx >> 6, q = (idx & 63) << 2;
        float4 v = *(const float4*)&Wb[(size_t)c * 256 + q];
        write4(Mt + (size_t)c * LDA_X + 2048 + q, v);
    } else {                            // Mt bias: [c][2304+j] = pool[j][2048+c]
        int idx = (bid - 2624) * 256 + t, c = idx >> 7, j4 = (idx & 127) << 2;
        float4 v;
        v.x = pool[(size_t)(j4 + 0) * D_POOL + 2048 + c];
        v.y = pool[(size_t)(j4 + 1) * D_POOL + 2048 + c];
        v.z = pool[(size_t)(j4 + 2) * D_POOL + 2048 + c];
        v.w = pool[(size_t)(j4 + 3) * D_POOL + 2048 + c];
        write4(Mt + (size_t)c * LDA_X + 2304 + j4, v);
    }
}

// ---- GEMM1: 64x64 tile, 4 waves (2x2 of 32x32), BK=64, K=256, 2-phase dbuf
__global__ __launch_bounds__(256) void k1_gemm(ushort_t* __restrict__ Xu,
                                               const ushort_t* __restrict__ Vb,
                                               const float* __restrict__ alpha) {
    __shared__ __align__(16) ushort_t As[2][64 * 64];
    __shared__ __align__(16) ushort_t Bs[2][64 * 64];
    const int t = threadIdx.x;
    const int w = t >> 6, l = t & 63, l16 = l & 15, l4 = l >> 4;
    const int wr = w >> 1, wc = w & 1;
    const int bm0 = blockIdx.y * 64, bn0 = blockIdx.x * 64;
    const ushort_t* A = Xu + 2048;      // hA segment, lda = 2816
    const int srow = t >> 3;            // 0..31
    const int schunk = (t & 7) ^ (srow & 7);  // source-side swizzle (rule #21)

    f32x4 acc[2][2];
    #pragma unroll
    for (int i = 0; i < 2; ++i)
        #pragma unroll
        for (int j = 0; j < 2; ++j) acc[i][j] = (f32x4){0.f, 0.f, 0.f, 0.f};

    auto stage = [&](int buf, int k0) {
        #pragma unroll
        for (int h = 0; h < 2; ++h) {
            gld16(A  + (size_t)(bm0 + srow + h * 32) * LDA_X + k0 + schunk * 8,
                  &As[buf][h * 2048 + w * 512]);
            gld16(Vb + (size_t)(bn0 + srow + h * 32) * 256   + k0 + schunk * 8,
                  &Bs[buf][h * 2048 + w * 512]);
        }
    };
    auto compute = [&](int buf) {
        bf16x8 af[2][2], bv[2][2];
        #pragma unroll
        for (int mi = 0; mi < 2; ++mi) {
            int arow = wr * 32 + mi * 16 + l16;
            #pragma unroll
            for (int ks = 0; ks < 2; ++ks)
                af[mi][ks] = *(const bf16x8*)&As[buf][arow * 64 + (((ks * 4 + l4) ^ (arow & 7)) << 3)];
        }
        #pragma unroll
        for (int ni = 0; ni < 2; ++ni) {
            int brow = wc * 32 + ni * 16 + l16;
            #pragma unroll
            for (int ks = 0; ks < 2; ++ks)
                bv[ni][ks] = *(const bf16x8*)&Bs[buf][brow * 64 + (((ks * 4 + l4) ^ (brow & 7)) << 3)];
        }
        #pragma unroll
        for (int ks = 0; ks < 2; ++ks)
            #pragma unroll
            for (int mi = 0; mi < 2; ++mi)
                #pragma unroll
                for (int ni = 0; ni < 2; ++ni)
                    acc[mi][ni] = __builtin_amdgcn_mfma_f32_16x16x32_bf16(af[mi][ks], bv[ni][ks], acc[mi][ni], 0, 0, 0);
    };

    stage(0, 0);
    __syncthreads();
    int cur = 0;
    #pragma unroll
    for (int it = 0; it < 3; ++it) {     // K=256 -> 4 steps
        stage(cur ^ 1, (it + 1) * 64);
        compute(cur);
        __syncthreads();                 // drains vmcnt+lgkm for the stage
        cur ^= 1;
    }
    compute(cur);

    __hip_bfloat16* Xb = (__hip_bfloat16*)Xu;
    #pragma unroll
    for (int mi = 0; mi < 2; ++mi)
        #pragma unroll
        for (int ni = 0; ni < 2; ++ni) {
            int kcol = bn0 + wc * 32 + ni * 16 + l16;
            #pragma unroll
            for (int e = 0; e < 4; ++e) {
                int b = bm0 + wr * 32 + mi * 16 + l4 * 4 + e;
                float v = acc[mi][ni][e] * alpha[(size_t)b * N_POOL + (kcol >> 2)];
                Xb[(size_t)b * LDA_X + kcol] = __float2bfloat16(v);
            }
        }
}

// ---- GEMM2: 64x64 tile, BK=64, split-K x4 (704 each), 2-phase dbuf
__global__ __launch_bounds__(256) void k2_gemm(const ushort_t* __restrict__ Xu,
                                               const ushort_t* __restrict__ Mt,
                                               float* __restrict__ part) {
    __shared__ __align__(16) ushort_t As[2][64 * 64];
    __shared__ __align__(16) ushort_t Bs[2][64 * 64];
    const int t = threadIdx.x;
    const int w = t >> 6, l = t & 63, l16 = l & 15, l4 = l >> 4;
    const int wr = w >> 1, wc = w & 1;
    const int bm0 = blockIdx.x * 64, bn0 = blockIdx.y * 64;
    const int kc0 = blockIdx.z * 704;
    const int srow = t >> 3;
    const int schunk = (t & 7) ^ (srow & 7);

    f32x4 acc[2][2];
    #pragma unroll
    for (int i = 0; i < 2; ++i)
        #pragma unroll
        for (int j = 0; j < 2; ++j) acc[i][j] = (f32x4){0.f, 0.f, 0.f, 0.f};

    auto stage = [&](int buf, int k0) {
        #pragma unroll
        for (int h = 0; h < 2; ++h) {
            gld16(Xu + (size_t)(bm0 + srow + h * 32) * LDA_X + k0 + schunk * 8,
                  &As[buf][h * 2048 + w * 512]);
            gld16(Mt + (size_t)(bn0 + srow + h * 32) * LDA_X + k0 + schunk * 8,
                  &Bs[buf][h * 2048 + w * 512]);
        }
    };
    auto compute = [&](int buf) {
        bf16x8 af[2][2], bv[2][2];
        #pragma unroll
        for (int mi = 0; mi < 2; ++mi) {
            int arow = wr * 32 + mi * 16 + l16;
            #pragma unroll
            for (int ks = 0; ks < 2; ++ks)
                af[mi][ks] = *(const bf16x8*)&As[buf][arow * 64 + (((ks * 4 + l4) ^ (arow & 7)) << 3)];
        }
        #pragma unroll
        for (int ni = 0; ni < 2; ++ni) {
            int brow = wc * 32 + ni * 16 + l16;
            #pragma unroll
            for (int ks = 0; ks < 2; ++ks)
                bv[ni][ks] = *(const bf16x8*)&Bs[buf][brow * 64 + (((ks * 4 + l4) ^ (brow & 7)) << 3)];
        }
        #pragma unroll
        for (int ks = 0; ks < 2; ++ks)
            #pragma unroll
            for (int mi = 0; mi < 2; ++mi)
                #pragma unroll
                for (int ni = 0; ni < 2; ++ni)
                    acc[mi][ni] = __builtin_amdgcn_mfma_f32_16x16x32_bf16(af[mi][ks], bv[ni][ks], acc[mi][ni], 0, 0, 0);
    };

    stage(0, kc0);
    __syncthreads();
    int cur = 0;
    for (int it = 0; it < 10; ++it) {    // K=704 -> 11 steps
        stage(cur ^ 1, kc0 + (it + 1) * 64);
        compute(cur);
        __syncthreads();
        cur ^= 1;
    }
    compute(cur);

    float* P = part + (size_t)blockIdx.z * (2048 * 256);
    #pragma unroll
    for (int mi = 0; mi < 2; ++mi)
        #pragma unroll
        for (int ni = 0; ni < 2; ++ni) {
            int c = bn0 + wc * 32 + ni * 16 + l16;
            #pragma unroll
            for (int e = 0; e < 4; ++e) {
                int b = bm0 + wr * 32 + mi * 16 + l4 * 4 + e;
                P[(size_t)b * 256 + c] = acc[mi][ni][e];
            }
        }
}

// ---- LN: sum 4 partials + b_base; residual; LayerNorm over 256; 1 wave/row
__global__ __launch_bounds__(256) void k3_ln(const float* __restrict__ part,
                                             const float* __restrict__ hA,
                                             const float* __restrict__ bb,
                                             const float* __restrict__ gamma_p,
                                             const float* __restrict__ lns,
                                             const float* __restrict__ lnb,
                                             float* __restrict__ out) {
    const int wave = threadIdx.x >> 6;
    const int lane = threadIdx.x & 63;
    const int b = blockIdx.x * 4 + wave;
    const float g = gamma_p[0];
    const size_t base = (size_t)b * 256 + lane * 4;

    float4 p = *(const float4*)&part[base];
    #pragma unroll
    for (int z = 1; z < 4; ++z) {
        float4 q = *(const float4*)&part[(size_t)z * 2048 * 256 + base];
        p.x += q.x; p.y += q.y; p.z += q.z; p.w += q.w;
    }
    float4 h  = *(const float4*)&hA[base];
    float4 b4 = *(const float4*)&bb[lane * 4];
    float y0 = h.x + g * (p.x + b4.x);
    float y1 = h.y + g * (p.y + b4.y);
    float y2 = h.z + g * (p.z + b4.z);
    float y3 = h.w + g * (p.w + b4.w);

    float sum = y0 + y1 + y2 + y3;
    float ss  = y0*y0 + y1*y1 + y2*y2 + y3*y3;
    #pragma unroll
    for (int off = 1; off < 64; off <<= 1) {
        sum += __shfl_xor(sum, off);
        ss  += __shfl_xor(ss, off);
    }
    float mu  = sum * (1.0f / 256.0f);
    float var = ss * (1.0f / 256.0f) - mu * mu;
    float inv = rsqrtf(var + 1e-5f);

    float4 sc = *(const float4*)&lns[lane * 4];
    float4 bi = *(const float4*)&lnb[lane * 4];
    float4 o;
    o.x = (y0 - mu) * inv * sc.x + bi.x;
    o.y = (y1 - mu) * inv * sc.y + bi.y;
    o.z = (y2 - mu) * inv * sc.z + bi.z;
    o.w = (y3 - mu) * inv * sc.w + bi.w;
    *(float4*)&out[base] = o;
}

extern "C" void kernel_launch(void* const* d_in, const int* in_sizes, int n_in,
                              void* d_out, int out_size, void* d_ws, size_t ws_size,
                              hipStream_t stream) {
    const float* hA    = (const float*)d_in[0];
    const float* pool  = (const float*)d_in[1];
    const float* alpha = (const float*)d_in[2];
    const float* Wb    = (const float*)d_in[3];
    const float* bb    = (const float*)d_in[4];
    const float* gamma = (const float*)d_in[5];
    const float* lns   = (const float*)d_in[6];
    const float* lnb   = (const float*)d_in[7];
    float* out = (float*)d_out;

    ushort_t* Xu = (ushort_t*)d_ws;                   // [2048][2816] bf16
    ushort_t* Vb = Xu + (size_t)2048 * 2816;          // [2048][256]  bf16
    ushort_t* Mt = Vb + (size_t)2048 * 256;           // [256][2816]  bf16
    float*  part = (float*)(Mt + (size_t)256 * 2816); // [4][2048][256] f32

    prep<<<2752, 256, 0, stream>>>(hA, pool, alpha, Wb, Xu, Vb, Mt);
    k1_gemm<<<dim3(32, 32), 256, 0, stream>>>(Xu, Vb, alpha);
    k2_gemm<<<dim3(32, 4, 4), 256, 0, stream>>>(Xu, Mt, part);
    k3_ln<<<512, 256, 0, stream>>>(part, hA, bb, gamma, lns, lnb, out);
}